// Round 8
// baseline (340.253 us; speedup 1.0000x reference)
//
#include <hip/hip_runtime.h>

constexpr int B = 2;
constexpr int N = 50000;
constexpr int D = 64;
constexpr int E = 800000;
constexpr int CAP = 96;        // Poisson(32) max degree over 50k nodes ~58; 96 = margin
constexpr int XG = 8;          // XCD groups
constexpr int NPG = N / XG;    // 6250 nodes per group
constexpr int CSTRIDE_PAD = 16;           // 1 counter per 64B line

// build geometry: block = 512 edges (2 per lane), 1563 build groups
// pgemm geometry: wave = 25 rows, block = 4 waves -> 1000 blocks = 125 groups
constexpr int ROWS_PER_WAVE = 25;
constexpr int BGROUPS = 1563;             // ceil(3125 chunks / 2)
constexpr int PGROUPS = 125;
constexpr int TOTAL_GROUPS = BGROUPS + PGROUPS;   // 1688

// ---- bf16 helpers (manual RTN) --------------------------------------------
__device__ __forceinline__ unsigned f2bf(float f) {
    unsigned u = __float_as_uint(f);
    return (u + 0x7FFFu + ((u >> 16) & 1u)) >> 16;
}
__device__ __forceinline__ float bfhi2f(unsigned bits) {
    return __uint_as_float(bits & 0xFFFF0000u);
}
__device__ __forceinline__ float bflo2f(unsigned bits) {
    return __uint_as_float(bits << 16);
}

__device__ __forceinline__ void acc8(float g, const uint4& r, float* a) {
    a[0] += g * bflo2f(r.x); a[1] += g * bfhi2f(r.x);
    a[2] += g * bflo2f(r.y); a[3] += g * bfhi2f(r.y);
    a[4] += g * bflo2f(r.z); a[5] += g * bfhi2f(r.z);
    a[6] += g * bflo2f(r.w); a[7] += g * bfhi2f(r.w);
}

// ===========================================================================
// 1) FUSED build + pgemm — build path UNCHANGED (110 us; atomic throughput
// floor: 1.6M returning device atomics at ~14.5 G/s, invariant across
// occupancy 42-66% and MLP 1-4). pgemm store: P quarter-major — node n's
// row = 4 quarters of 64 B; quarter q = [batch0 f[16q,16q+16): 8 dw]
// [batch1 same: 8 dw]. Gather pass q then reads EXACTLY one dense 64 B
// line per entry, and all of pass q's random reads live in a 3.2 MB slab.
// ===========================================================================
__global__ __launch_bounds__(256) void build_pgemm_fused(
    const int2* __restrict__ edges, const float* __restrict__ status,
    int* __restrict__ counts, unsigned* __restrict__ slots,
    const float* __restrict__ prev, const float* __restrict__ W,
    unsigned* __restrict__ P32, int cstride)
{
    int grp = blockIdx.x >> 3;
    int sub8 = blockIdx.x & 7;
    int t = threadIdx.x;

    int cyc = grp / 13, pos = grp % 13;
    bool is_pgemm = (pos == 12) && (grp < PGROUPS * 13);

    if (!is_pgemm) {
        int b = (grp < PGROUPS * 13) ? (cyc * 12 + pos) : (1500 + (grp - PGROUPS * 13));
        int e0 = b * 512 + t;
        int e1 = e0 + 256;
        bool has1 = (e1 < E);

        int2 uv0 = edges[e0];
        float st0 = status[e0];
        int2 uv1 = has1 ? edges[e1] : uv0;
        float st1 = has1 ? status[e1] : 0.f;
        unsigned gb0 = f2bf(st0) << 16;
        unsigned gb1 = f2bf(st1) << 16;

        bool du0 = (uv0.x / NPG == sub8);
        bool dv0 = (uv0.y / NPG == sub8);
        bool du1 = has1 && (uv1.x / NPG == sub8);
        bool dv1 = has1 && (uv1.y / NPG == sub8);

        int pu0 = CAP, pv0 = CAP, pu1 = CAP, pv1 = CAP;
        if (du0) pu0 = atomicAdd(&counts[(size_t)uv0.x * cstride], 1);
        if (dv0) pv0 = atomicAdd(&counts[(size_t)uv0.y * cstride], 1);
        if (du1) pu1 = atomicAdd(&counts[(size_t)uv1.x * cstride], 1);
        if (dv1) pv1 = atomicAdd(&counts[(size_t)uv1.y * cstride], 1);
        if (du0 && pu0 < CAP) slots[(size_t)uv0.x * CAP + pu0] = gb0 | (unsigned)uv0.y;
        if (dv0 && pv0 < CAP) slots[(size_t)uv0.y * CAP + pv0] = gb0 | (unsigned)uv0.x;
        if (du1 && pu1 < CAP) slots[(size_t)uv1.x * CAP + pu1] = gb1 | (unsigned)uv1.y;
        if (dv1 && pv1 < CAP) slots[(size_t)uv1.y * CAP + pv1] = gb1 | (unsigned)uv1.x;
    } else {
        int pb = cyc * 8 + sub8;
        int wave = t >> 6, lane = t & 63;

        const float4* W4 = (const float4*)W;
        float4 w[16];
#pragma unroll
        for (int q = 0; q < 16; ++q) w[q] = W4[lane * 16 + q];

        int row0 = pb * (4 * ROWS_PER_WAVE) + wave * ROWS_PER_WAVE;
        for (int r = 0; r < ROWS_PER_WAVE; ++r) {
            int row = __builtin_amdgcn_readfirstlane(row0 + r);   // in [0, B*N)
            const float* pr = prev + (size_t)row * D;   // wave-uniform -> s_load

            float acc = 0.f;
#pragma unroll
            for (int d = 0; d < D; ++d) {
                const float4& wq = w[d >> 2];
                float wd = (d & 3) == 0 ? wq.x : (d & 3) == 1 ? wq.y
                         : (d & 3) == 2 ? wq.z : wq.w;
                acc += pr[d] * wd;
            }

            float partner = __shfl_xor(acc, 1, 64);     // feature lane^1
            if ((lane & 1) == 0) {
                // quarter-major store: f2 = feature pair, quarter = f2>>3
                int bsel = row >= N;                    // wave-uniform
                int n = row - bsel * N;
                int f2 = lane >> 1;
                P32[(size_t)n * 64 + (f2 >> 3) * 16 + bsel * 8 + (f2 & 7)]
                    = f2bf(acc) | (f2bf(partner) << 16);
            }
        }
    }
}

// ===========================================================================
// 2) Gather, pass-per-launch L2-resident version. R5/R6/R7 model: gather
// time = (L2-miss bytes)/~4 TB/s LLC-fabric rate; P (12.8 MB) can't be
// L2-resident whole (4 MB/XCD) -> ~70% miss on random reads. Fix: 4
// SEQUENTIAL LAUNCHES; launch q's random reads touch only slab q (3.2 MB
// < 4 MB L2) -> after compulsory warm, all ~32x re-reads are L2 hits. No
// dispatch-order assumption (stream serialization gives phase alignment).
// Per entry per pass: one dense 64 B line (4 lanes x uint4). Streams
// (slots/node/edgef/out) nt so they can't evict the slab.
// R6's failure causes removed: pass loop was INSIDE blocks (no phase
// alignment) and slabs were 32 B-fragmented (FETCH 534 MB).
// ===========================================================================
__global__ __launch_bounds__(256) void gather_pass(
    const uint4* __restrict__ P4,     // N rows x 16 uint4; (n,q) at n*16+q*4
    const int* __restrict__ counts,
    const unsigned* __restrict__ slots,
    const float* __restrict__ node,
    const float* __restrict__ edgef,
    float* __restrict__ out, int cstride, int pass)
{
    __shared__ float xs[4][2][16];

    int t = threadIdx.x;
    int wave = t >> 6, lane = t & 63;
    int n = blockIdx.x * 4 + wave;    // grid = N/4 = 12500 exact
    int s = lane >> 2;                // entry sub-index, 16-wide
    int j = lane & 3;                 // uint4 within the 64 B quarter-line

    // epilogue streams hoisted (lanes 0-31), nt: keep out of L2
    float nd = 0.f, ef = 0.f;
    size_t oidx = 0;
    if (lane < 32) {
        int batch = lane >> 4, f = lane & 15;
        oidx = ((size_t)batch * N + n) * D + pass * 16 + f;
        nd = __builtin_nontemporal_load(node + oidx);
        ef = __builtin_nontemporal_load(edgef + oidx);
    }

    int cnt = min(counts[(size_t)n * cstride], CAP);
    size_t sbase = (size_t)n * CAP;

    float a[8];
#pragma unroll
    for (int i = 0; i < 8; ++i) a[i] = 0.f;

    size_t pbase = (size_t)pass * 4 + j;
    for (int k = s; k < cnt; k += 16) {
        unsigned ent = __builtin_nontemporal_load(slots + sbase + k); // 4 lanes same addr
        float g = bfhi2f(ent);
        unsigned m = ent & 0xFFFFu;                  // node id < 50000 < 65536
        uint4 r = P4[(size_t)m * 16 + pbase];        // L2-resident slab read
        acc8(g, r, a);
    }

    // reduce across 16 subs (lane bits 2..5)
#pragma unroll
    for (int mm = 4; mm <= 32; mm <<= 1) {
#pragma unroll
        for (int i = 0; i < 8; ++i) a[i] += __shfl_xor(a[i], mm, 64);
    }

    if (s == 0) {   // lanes 0-3: batch = j>>1, feature offset (j&1)*8
        *(float4*)&xs[wave][j >> 1][(j & 1) * 8]     = make_float4(a[0], a[1], a[2], a[3]);
        *(float4*)&xs[wave][j >> 1][(j & 1) * 8 + 4] = make_float4(a[4], a[5], a[6], a[7]);
    }
    // same-wave LDS dependence: compiler inserts lgkmcnt wait; no barrier.
    if (lane < 32) {
        float sv = xs[wave][lane >> 4][lane & 15];
        float y = nd + sv + ef;
        float rr = (y >= 0.f) ? y : 0.01f * y;
        __builtin_nontemporal_store(rr, out + oidx);
    }
}

// ===========================================================================
// LAST-RESORT FALLBACK (tiny ws): atomic scatter + separate gemm (fp32 exact)
// ===========================================================================
__device__ inline void atomic_add4(float* p, float4 val, float g) {
    atomicAdd(p + 0, val.x * g);
    atomicAdd(p + 1, val.y * g);
    atomicAdd(p + 2, val.z * g);
    atomicAdd(p + 3, val.w * g);
}

__global__ __launch_bounds__(256) void scatter_kernel(
    const float* __restrict__ prev,
    const int2* __restrict__ edges,
    const float* __restrict__ status,
    float* __restrict__ nbr)
{
    int idx = blockIdx.x * 256 + threadIdx.x;
    int e = idx >> 4;
    int q = idx & 15;
    if (e >= E) return;
    int2 uv = edges[e];
    float g = status[e];
    const float4* p0 = (const float4*)prev;
    const float4* p1 = (const float4*)(prev + (size_t)N * D);
    float4 pu0 = p0[(size_t)uv.x * 16 + q];
    float4 pv0 = p0[(size_t)uv.y * 16 + q];
    float4 pu1 = p1[(size_t)uv.x * 16 + q];
    float4 pv1 = p1[(size_t)uv.y * 16 + q];
    float* n0 = nbr;
    float* n1 = nbr + (size_t)N * D;
    int off_v = uv.y * D + q * 4;
    int off_u = uv.x * D + q * 4;
    atomic_add4(n0 + off_v, pu0, g);
    atomic_add4(n0 + off_u, pv0, g);
    atomic_add4(n1 + off_v, pu1, g);
    atomic_add4(n1 + off_u, pv1, g);
}

__global__ __launch_bounds__(256) void gemm_relu_kernel(
    float* __restrict__ out,
    const float* __restrict__ node,
    const float* __restrict__ edgef,
    const float* __restrict__ W)
{
    __shared__ float Wl[D][D + 1];
    __shared__ float xs[4][D];
    int t = threadIdx.x;
    for (int i = t; i < D * D; i += 256) Wl[i >> 6][i & 63] = W[i];
    int wave = t >> 6, lane = t & 63;
    int row = blockIdx.x * 4 + wave;
    size_t base = (size_t)row * D;
    float x = out[base + lane];
    xs[wave][lane] = x;
    __syncthreads();
    float acc = 0.f;
#pragma unroll
    for (int d = 0; d < D; ++d) acc += xs[wave][d] * Wl[lane][d];
    float y = node[base + lane] + acc + edgef[base + lane];
    out[base + lane] = (y >= 0.f) ? y : 0.01f * y;
}

// ===========================================================================
extern "C" void kernel_launch(void* const* d_in, const int* in_sizes, int n_in,
                              void* d_out, int out_size, void* d_ws, size_t ws_size,
                              hipStream_t stream) {
    const float* prev   = (const float*)d_in[0];
    const int*   edges  = (const int*)d_in[1];
    const float* node   = (const float*)d_in[2];
    const float* edgef  = (const float*)d_in[3];
    const float* status = (const float*)d_in[4];
    const float* W      = (const float*)d_in[5];
    float* out = (float*)d_out;

    const int2* edges2 = (const int2*)edges;

    // ws: slots[N*CAP] u32 | counts[N*cstride] i32 | P32[N*64] u32
    size_t slots_bytes  = (size_t)N * CAP * sizeof(unsigned);    // 19.2 MB
    size_t p_bytes      = (size_t)N * 64 * sizeof(unsigned);     // 12.8 MB
    size_t counts_pad   = (size_t)N * CSTRIDE_PAD * sizeof(int); // 3.2 MB
    size_t counts_min   = (size_t)N * sizeof(int);               // 0.2 MB

    int cstride;
    size_t counts_bytes;
    if (ws_size >= slots_bytes + counts_pad + p_bytes) {
        cstride = CSTRIDE_PAD; counts_bytes = counts_pad;
    } else if (ws_size >= slots_bytes + counts_min + p_bytes) {
        cstride = 1; counts_bytes = counts_min;
    } else {
        hipMemsetAsync(out, 0, (size_t)B * N * D * sizeof(float), stream);
        scatter_kernel<<<(E * 16) / 256, 256, 0, stream>>>(prev, edges2, status, out);
        gemm_relu_kernel<<<(B * N) / 4, 256, 0, stream>>>(out, node, edgef, W);
        return;
    }

    unsigned* slots = (unsigned*)d_ws;
    int* counts = (int*)((char*)d_ws + slots_bytes);
    unsigned* P32 = (unsigned*)((char*)d_ws + slots_bytes + counts_bytes);

    hipMemsetAsync(counts, 0, counts_bytes, stream);
    build_pgemm_fused<<<TOTAL_GROUPS * 8, 256, 0, stream>>>(
        edges2, status, counts, slots, prev, W, P32, cstride);
    for (int pass = 0; pass < 4; ++pass) {
        gather_pass<<<N / 4, 256, 0, stream>>>(
            (const uint4*)P32, counts, slots, node, edgef, out, cstride, pass);
    }
}

// Round 9
// 336.514 us; speedup vs baseline: 1.0111x; 1.0111x over previous
//
#include <hip/hip_runtime.h>

constexpr int B = 2;
constexpr int N = 50000;
constexpr int D = 64;
constexpr int E = 800000;
constexpr int CAP = 96;        // Poisson(32) max degree over 50k nodes ~58; 96 = margin
constexpr int CSTRIDE_PAD = 16;           // 1 counter per 64B line

// FLAT build: 1563 blocks x 512 edges (2/lane, all lanes active, no filter).
// pgemm: wave = 50 rows, block = 4 waves = 200 rows -> 500 blocks.
// Interleave cycle of 4 = 3 build + 1 pgemm; grid = 521*4 = 2084.
constexpr int ROWS_PER_WAVE = 50;
constexpr int BBLOCKS = 1563;
constexpr int PBLOCKS2 = 500;
constexpr int CYCLES = 521;               // ceil(BBLOCKS/3)
constexpr int GRID = CYCLES * 4;          // 2084

// ---- bf16 helpers (manual RTN) --------------------------------------------
__device__ __forceinline__ unsigned f2bf(float f) {
    unsigned u = __float_as_uint(f);
    return (u + 0x7FFFu + ((u >> 16) & 1u)) >> 16;
}
__device__ __forceinline__ float bfhi2f(unsigned bits) {
    return __uint_as_float(bits & 0xFFFF0000u);
}
__device__ __forceinline__ float bflo2f(unsigned bits) {
    return __uint_as_float(bits << 16);
}

__device__ __forceinline__ void acc8(float g, const uint4& r, float* a) {
    a[0] += g * bflo2f(r.x); a[1] += g * bfhi2f(r.x);
    a[2] += g * bflo2f(r.y); a[3] += g * bfhi2f(r.y);
    a[4] += g * bflo2f(r.z); a[5] += g * bfhi2f(r.z);
    a[6] += g * bflo2f(r.w); a[7] += g * bfhi2f(r.w);
}

// ===========================================================================
// 1) FUSED flat build + pgemm. ABLATION of the 8x replica/partition scheme:
// same 1.6M atomic transactions, but issued from 8x fewer wave-instructions
// (64/64 lanes active vs ~8/64), 8x fewer blocks, 8x less edge/status fetch.
// Discriminates "instruction/issue-bound" vs "atomic-transaction floor".
// pgemm: LDS-free W-in-VGPR row kernel (hidden under build since R2);
// P layout = R7 batch-interleaved 256 B node rows.
// ===========================================================================
__global__ __launch_bounds__(256) void build_pgemm_fused(
    const int2* __restrict__ edges, const float* __restrict__ status,
    int* __restrict__ counts, unsigned* __restrict__ slots,
    const float* __restrict__ prev, const float* __restrict__ W,
    unsigned* __restrict__ P32, int cstride)
{
    int cyc = blockIdx.x >> 2;
    int pos = blockIdx.x & 3;
    int t = threadIdx.x;

    if (pos < 3) {
        // ---- flat build: block b in [0,1563), edges [b*512, b*512+512) ----
        int b = cyc * 3 + pos;            // cyc<521 -> b<=1562 exactly
        int e0 = b * 512 + t;             // <= 799999 always
        int e1 = e0 + 256;
        bool has1 = (e1 < E);             // uniform false only in block 1562

        int2 uv0 = edges[e0];
        float st0 = status[e0];
        int2 uv1 = has1 ? edges[e1] : uv0;
        float st1 = has1 ? status[e1] : 0.f;
        unsigned gb0 = f2bf(st0) << 16;
        unsigned gb1 = f2bf(st1) << 16;

        // 4 independent atomic round trips in flight before any consumer
        int pu0 = atomicAdd(&counts[(size_t)uv0.x * cstride], 1);
        int pv0 = atomicAdd(&counts[(size_t)uv0.y * cstride], 1);
        int pu1 = CAP, pv1 = CAP;
        if (has1) {
            pu1 = atomicAdd(&counts[(size_t)uv1.x * cstride], 1);
            pv1 = atomicAdd(&counts[(size_t)uv1.y * cstride], 1);
        }
        if (pu0 < CAP) slots[(size_t)uv0.x * CAP + pu0] = gb0 | (unsigned)uv0.y;
        if (pv0 < CAP) slots[(size_t)uv0.y * CAP + pv0] = gb0 | (unsigned)uv0.x;
        if (has1 && pu1 < CAP) slots[(size_t)uv1.x * CAP + pu1] = gb1 | (unsigned)uv1.y;
        if (has1 && pv1 < CAP) slots[(size_t)uv1.y * CAP + pv1] = gb1 | (unsigned)uv1.x;
    } else {
        // ---- pgemm: pb = cyc in [0,500), wave handles 50 rows -------------
        int pb = cyc;
        if (pb >= PBLOCKS2) return;       // 21 idle blocks, exit fast
        int wave = t >> 6, lane = t & 63;

        const float4* W4 = (const float4*)W;
        float4 w[16];
#pragma unroll
        for (int q = 0; q < 16; ++q) w[q] = W4[lane * 16 + q];

        int row0 = pb * (4 * ROWS_PER_WAVE) + wave * ROWS_PER_WAVE;
        for (int r = 0; r < ROWS_PER_WAVE; ++r) {
            int row = __builtin_amdgcn_readfirstlane(row0 + r);   // in [0, B*N)
            const float* pr = prev + (size_t)row * D;   // wave-uniform -> s_load

            float acc = 0.f;
#pragma unroll
            for (int d = 0; d < D; ++d) {
                const float4& wq = w[d >> 2];
                float wd = (d & 3) == 0 ? wq.x : (d & 3) == 1 ? wq.y
                         : (d & 3) == 2 ? wq.z : wq.w;
                acc += pr[d] * wd;
            }

            float partner = __shfl_xor(acc, 1, 64);     // feature lane^1
            if ((lane & 1) == 0) {
                // batch-interleaved: node n block of 64 dw = [b0:32][b1:32]
                int bsel = row >= N;                    // wave-uniform
                int n = row - bsel * N;
                P32[(size_t)n * 64 + bsel * 32 + (lane >> 1)]
                    = f2bf(acc) | (f2bf(partner) << 16);
            }
        }
    }
}

// ===========================================================================
// 2) Gather — R7 version VERBATIM (96 us, measured floor: time = L2-miss
// bytes / ~4 TB/s LLC service; MLP null (R5), slicing regressed (R6, R8),
// nt + dense 256 B rows = best measured). Do not touch.
// ===========================================================================
__global__ __launch_bounds__(256) void gather_final(
    const uint4* __restrict__ P4,     // (N) rows of 16 uint4 = 256 B
    const int* __restrict__ counts,
    const unsigned* __restrict__ slots,
    const float* __restrict__ node,
    const float* __restrict__ edgef,
    float* __restrict__ out, int cstride)
{
    __shared__ float xs[4][2][D];

    int t = threadIdx.x;
    int wave = t >> 6, lane = t & 63;
    int n = blockIdx.x * 4 + wave;    // grid = N/4 = 12500 exact
    int j = lane & 7;                 // uint4 chunk within 128 B half-row
    int sub = lane >> 3;              // 8-wide entry parallelism

    size_t b0 = (size_t)n * D + lane;
    size_t b1 = (size_t)N * D + b0;
    float nd0 = __builtin_nontemporal_load(node + b0);
    float ef0 = __builtin_nontemporal_load(edgef + b0);
    float nd1 = __builtin_nontemporal_load(node + b1);
    float ef1 = __builtin_nontemporal_load(edgef + b1);

    int cnt = min(counts[(size_t)n * cstride], CAP);
    size_t sbase = (size_t)n * CAP;

    float a0[8], a1[8];
#pragma unroll
    for (int i = 0; i < 8; ++i) { a0[i] = 0.f; a1[i] = 0.f; }

    int last = cnt - 1;
    int nch = (cnt + 31) >> 5;        // chunks of 32 entries; avg cnt=32 -> 1
    for (int c = 0; c < nch; ++c) {
        int k0 = sub + c * 32;
        unsigned e0 = __builtin_nontemporal_load(slots + sbase + min(k0,      last));
        unsigned e1 = __builtin_nontemporal_load(slots + sbase + min(k0 + 8,  last));
        unsigned e2 = __builtin_nontemporal_load(slots + sbase + min(k0 + 16, last));
        unsigned e3 = __builtin_nontemporal_load(slots + sbase + min(k0 + 24, last));
        float g0 = (k0      < cnt) ? bfhi2f(e0) : 0.f;
        float g1 = (k0 + 8  < cnt) ? bfhi2f(e1) : 0.f;
        float g2 = (k0 + 16 < cnt) ? bfhi2f(e2) : 0.f;
        float g3 = (k0 + 24 < cnt) ? bfhi2f(e3) : 0.f;
        unsigned m0 = e0 & 0xFFFFu, m1 = e1 & 0xFFFFu;
        unsigned m2 = e2 & 0xFFFFu, m3 = e3 & 0xFFFFu;
        uint4 r00 = P4[(size_t)m0 * 16 + j];
        uint4 r10 = P4[(size_t)m0 * 16 + 8 + j];
        uint4 r01 = P4[(size_t)m1 * 16 + j];
        uint4 r11 = P4[(size_t)m1 * 16 + 8 + j];
        uint4 r02 = P4[(size_t)m2 * 16 + j];
        uint4 r12 = P4[(size_t)m2 * 16 + 8 + j];
        uint4 r03 = P4[(size_t)m3 * 16 + j];
        uint4 r13 = P4[(size_t)m3 * 16 + 8 + j];
        acc8(g0, r00, a0); acc8(g0, r10, a1);
        acc8(g1, r01, a0); acc8(g1, r11, a1);
        acc8(g2, r02, a0); acc8(g2, r12, a1);
        acc8(g3, r03, a0); acc8(g3, r13, a1);
    }

#pragma unroll
    for (int m = 8; m <= 32; m <<= 1) {
#pragma unroll
        for (int i = 0; i < 8; ++i) {
            a0[i] += __shfl_xor(a0[i], m, 64);
            a1[i] += __shfl_xor(a1[i], m, 64);
        }
    }

    if (sub == 0) {
        *(float4*)&xs[wave][0][j * 8]     = make_float4(a0[0], a0[1], a0[2], a0[3]);
        *(float4*)&xs[wave][0][j * 8 + 4] = make_float4(a0[4], a0[5], a0[6], a0[7]);
        *(float4*)&xs[wave][1][j * 8]     = make_float4(a1[0], a1[1], a1[2], a1[3]);
        *(float4*)&xs[wave][1][j * 8 + 4] = make_float4(a1[4], a1[5], a1[6], a1[7]);
    }
    // same-wave LDS dependence: compiler inserts lgkmcnt wait; no barrier.
    float s0 = xs[wave][0][lane];
    float s1 = xs[wave][1][lane];

    float y0 = nd0 + s0 + ef0;
    float y1 = nd1 + s1 + ef1;
    float r0 = (y0 >= 0.f) ? y0 : 0.01f * y0;
    float r1 = (y1 >= 0.f) ? y1 : 0.01f * y1;
    __builtin_nontemporal_store(r0, out + b0);
    __builtin_nontemporal_store(r1, out + b1);
}

// ===========================================================================
// LAST-RESORT FALLBACK (tiny ws): atomic scatter + separate gemm (fp32 exact)
// ===========================================================================
__device__ inline void atomic_add4(float* p, float4 val, float g) {
    atomicAdd(p + 0, val.x * g);
    atomicAdd(p + 1, val.y * g);
    atomicAdd(p + 2, val.z * g);
    atomicAdd(p + 3, val.w * g);
}

__global__ __launch_bounds__(256) void scatter_kernel(
    const float* __restrict__ prev,
    const int2* __restrict__ edges,
    const float* __restrict__ status,
    float* __restrict__ nbr)
{
    int idx = blockIdx.x * 256 + threadIdx.x;
    int e = idx >> 4;
    int q = idx & 15;
    if (e >= E) return;
    int2 uv = edges[e];
    float g = status[e];
    const float4* p0 = (const float4*)prev;
    const float4* p1 = (const float4*)(prev + (size_t)N * D);
    float4 pu0 = p0[(size_t)uv.x * 16 + q];
    float4 pv0 = p0[(size_t)uv.y * 16 + q];
    float4 pu1 = p1[(size_t)uv.x * 16 + q];
    float4 pv1 = p1[(size_t)uv.y * 16 + q];
    float* n0 = nbr;
    float* n1 = nbr + (size_t)N * D;
    int off_v = uv.y * D + q * 4;
    int off_u = uv.x * D + q * 4;
    atomic_add4(n0 + off_v, pu0, g);
    atomic_add4(n0 + off_u, pv0, g);
    atomic_add4(n1 + off_v, pu1, g);
    atomic_add4(n1 + off_u, pv1, g);
}

__global__ __launch_bounds__(256) void gemm_relu_kernel(
    float* __restrict__ out,
    const float* __restrict__ node,
    const float* __restrict__ edgef,
    const float* __restrict__ W)
{
    __shared__ float Wl[D][D + 1];
    __shared__ float xs[4][D];
    int t = threadIdx.x;
    for (int i = t; i < D * D; i += 256) Wl[i >> 6][i & 63] = W[i];
    int wave = t >> 6, lane = t & 63;
    int row = blockIdx.x * 4 + wave;
    size_t base = (size_t)row * D;
    float x = out[base + lane];
    xs[wave][lane] = x;
    __syncthreads();
    float acc = 0.f;
#pragma unroll
    for (int d = 0; d < D; ++d) acc += xs[wave][d] * Wl[lane][d];
    float y = node[base + lane] + acc + edgef[base + lane];
    out[base + lane] = (y >= 0.f) ? y : 0.01f * y;
}

// ===========================================================================
extern "C" void kernel_launch(void* const* d_in, const int* in_sizes, int n_in,
                              void* d_out, int out_size, void* d_ws, size_t ws_size,
                              hipStream_t stream) {
    const float* prev   = (const float*)d_in[0];
    const int*   edges  = (const int*)d_in[1];
    const float* node   = (const float*)d_in[2];
    const float* edgef  = (const float*)d_in[3];
    const float* status = (const float*)d_in[4];
    const float* W      = (const float*)d_in[5];
    float* out = (float*)d_out;

    const int2* edges2 = (const int2*)edges;

    // ws: slots[N*CAP] u32 | counts[N*cstride] i32 | P32[N*64] u32
    size_t slots_bytes  = (size_t)N * CAP * sizeof(unsigned);    // 19.2 MB
    size_t p_bytes      = (size_t)N * 64 * sizeof(unsigned);     // 12.8 MB
    size_t counts_pad   = (size_t)N * CSTRIDE_PAD * sizeof(int); // 3.2 MB
    size_t counts_min   = (size_t)N * sizeof(int);               // 0.2 MB

    int cstride;
    size_t counts_bytes;
    if (ws_size >= slots_bytes + counts_pad + p_bytes) {
        cstride = CSTRIDE_PAD; counts_bytes = counts_pad;
    } else if (ws_size >= slots_bytes + counts_min + p_bytes) {
        cstride = 1; counts_bytes = counts_min;
    } else {
        hipMemsetAsync(out, 0, (size_t)B * N * D * sizeof(float), stream);
        scatter_kernel<<<(E * 16) / 256, 256, 0, stream>>>(prev, edges2, status, out);
        gemm_relu_kernel<<<(B * N) / 4, 256, 0, stream>>>(out, node, edgef, W);
        return;
    }

    unsigned* slots = (unsigned*)d_ws;
    int* counts = (int*)((char*)d_ws + slots_bytes);
    unsigned* P32 = (unsigned*)((char*)d_ws + slots_bytes + counts_bytes);

    hipMemsetAsync(counts, 0, counts_bytes, stream);
    build_pgemm_fused<<<GRID, 256, 0, stream>>>(
        edges2, status, counts, slots, prev, W, P32, cstride);
    gather_final<<<N / 4, 256, 0, stream>>>(
        (const uint4*)P32, counts, slots, node, edgef, out, cstride);
}

// Round 10
// 259.653 us; speedup vs baseline: 1.3104x; 1.2960x over previous
//
#include <hip/hip_runtime.h>

constexpr int B = 2;
constexpr int N = 50000;
constexpr int D = 64;
constexpr int E = 800000;
constexpr int CAP = 96;        // Poisson(32) max degree over 50k nodes ~58; 96 = margin
constexpr int XG = 8;          // XCD groups
constexpr int NPG = N / XG;    // 6250 nodes per group
constexpr int CSTRIDE_PAD = 16;           // 1 counter per 64B line

// build geometry: block = 512 edges (2 per lane), 1563 build groups
// pgemm geometry: wave = 25 rows, block = 4 waves -> 1000 blocks = 125 groups
constexpr int ROWS_PER_WAVE = 25;
constexpr int BGROUPS = 1563;             // ceil(3125 chunks / 2)
constexpr int PGROUPS = 125;
constexpr int TOTAL_GROUPS = BGROUPS + PGROUPS;   // 1688

// ---- bf16 helpers (manual RTN) --------------------------------------------
__device__ __forceinline__ unsigned f2bf(float f) {
    unsigned u = __float_as_uint(f);
    return (u + 0x7FFFu + ((u >> 16) & 1u)) >> 16;
}
__device__ __forceinline__ float bfhi2f(unsigned bits) {
    return __uint_as_float(bits & 0xFFFF0000u);
}
__device__ __forceinline__ float bflo2f(unsigned bits) {
    return __uint_as_float(bits << 16);
}

__device__ __forceinline__ void acc8(float g, const uint4& r, float* a) {
    a[0] += g * bflo2f(r.x); a[1] += g * bfhi2f(r.x);
    a[2] += g * bflo2f(r.y); a[3] += g * bfhi2f(r.y);
    a[4] += g * bflo2f(r.z); a[5] += g * bfhi2f(r.z);
    a[6] += g * bflo2f(r.w); a[7] += g * bfhi2f(r.w);
}

// ===========================================================================
// 1) FUSED build + pgemm — R7 configuration (best measured, 261 us total).
// Build: XCD-PARTITIONED slot build (8 replicas, blockIdx&7 = partition).
// R9 flat-build A/B proved the partition's value: counter/slot RMW lines
// stay XCD-local (flat: +80 us, WRITE +28 MB from line ownership migration).
// Padding/MLP/occupancy ablations all null -> 110 us = atomic floor.
// pgemm: LDS-free W-in-VGPR row kernel (hidden under build since R2);
// P layout: batch-interleaved 256 B node rows [b0:32 dw][b1:32 dw].
// ===========================================================================
__global__ __launch_bounds__(256) void build_pgemm_fused(
    const int2* __restrict__ edges, const float* __restrict__ status,
    int* __restrict__ counts, unsigned* __restrict__ slots,
    const float* __restrict__ prev, const float* __restrict__ W,
    unsigned* __restrict__ P32, int cstride)
{
    int grp = blockIdx.x >> 3;
    int sub8 = blockIdx.x & 7;
    int t = threadIdx.x;

    int cyc = grp / 13, pos = grp % 13;
    bool is_pgemm = (pos == 12) && (grp < PGROUPS * 13);

    if (!is_pgemm) {
        int b = (grp < PGROUPS * 13) ? (cyc * 12 + pos) : (1500 + (grp - PGROUPS * 13));
        int e0 = b * 512 + t;
        int e1 = e0 + 256;
        bool has1 = (e1 < E);

        int2 uv0 = edges[e0];
        float st0 = status[e0];
        int2 uv1 = has1 ? edges[e1] : uv0;
        float st1 = has1 ? status[e1] : 0.f;
        unsigned gb0 = f2bf(st0) << 16;
        unsigned gb1 = f2bf(st1) << 16;

        bool du0 = (uv0.x / NPG == sub8);
        bool dv0 = (uv0.y / NPG == sub8);
        bool du1 = has1 && (uv1.x / NPG == sub8);
        bool dv1 = has1 && (uv1.y / NPG == sub8);

        int pu0 = CAP, pv0 = CAP, pu1 = CAP, pv1 = CAP;
        if (du0) pu0 = atomicAdd(&counts[(size_t)uv0.x * cstride], 1);
        if (dv0) pv0 = atomicAdd(&counts[(size_t)uv0.y * cstride], 1);
        if (du1) pu1 = atomicAdd(&counts[(size_t)uv1.x * cstride], 1);
        if (dv1) pv1 = atomicAdd(&counts[(size_t)uv1.y * cstride], 1);
        if (du0 && pu0 < CAP) slots[(size_t)uv0.x * CAP + pu0] = gb0 | (unsigned)uv0.y;
        if (dv0 && pv0 < CAP) slots[(size_t)uv0.y * CAP + pv0] = gb0 | (unsigned)uv0.x;
        if (du1 && pu1 < CAP) slots[(size_t)uv1.x * CAP + pu1] = gb1 | (unsigned)uv1.y;
        if (dv1 && pv1 < CAP) slots[(size_t)uv1.y * CAP + pv1] = gb1 | (unsigned)uv1.x;
    } else {
        int pb = cyc * 8 + sub8;
        int wave = t >> 6, lane = t & 63;

        const float4* W4 = (const float4*)W;
        float4 w[16];
#pragma unroll
        for (int q = 0; q < 16; ++q) w[q] = W4[lane * 16 + q];

        int row0 = pb * (4 * ROWS_PER_WAVE) + wave * ROWS_PER_WAVE;
        for (int r = 0; r < ROWS_PER_WAVE; ++r) {
            int row = __builtin_amdgcn_readfirstlane(row0 + r);   // in [0, B*N)
            const float* pr = prev + (size_t)row * D;   // wave-uniform -> s_load

            float acc = 0.f;
#pragma unroll
            for (int d = 0; d < D; ++d) {
                const float4& wq = w[d >> 2];
                float wd = (d & 3) == 0 ? wq.x : (d & 3) == 1 ? wq.y
                         : (d & 3) == 2 ? wq.z : wq.w;
                acc += pr[d] * wd;
            }

            float partner = __shfl_xor(acc, 1, 64);     // feature lane^1
            if ((lane & 1) == 0) {
                // batch-interleaved: node n block of 64 dw = [b0:32][b1:32]
                int bsel = row >= N;                    // wave-uniform
                int n = row - bsel * N;
                P32[(size_t)n * 64 + bsel * 32 + (lane >> 1)]
                    = f2bf(acc) | (f2bf(partner) << 16);
            }
        }
    }
}

// ===========================================================================
// 2) Gather — R7 version VERBATIM (best measured ~100 us; at the LLC
// random-line service floor: 410 MB / ~4 TB/s. MLP null (R5), in-block
// slicing +50 us (R6), launch-split slicing +120 us (R8); nt + dense
// 256 B rows = best). Do not touch.
// ===========================================================================
__global__ __launch_bounds__(256) void gather_final(
    const uint4* __restrict__ P4,     // (N) rows of 16 uint4 = 256 B
    const int* __restrict__ counts,
    const unsigned* __restrict__ slots,
    const float* __restrict__ node,
    const float* __restrict__ edgef,
    float* __restrict__ out, int cstride)
{
    __shared__ float xs[4][2][D];

    int t = threadIdx.x;
    int wave = t >> 6, lane = t & 63;
    int n = blockIdx.x * 4 + wave;    // grid = N/4 = 12500 exact
    int j = lane & 7;                 // uint4 chunk within 128 B half-row
    int sub = lane >> 3;              // 8-wide entry parallelism

    size_t b0 = (size_t)n * D + lane;
    size_t b1 = (size_t)N * D + b0;
    float nd0 = __builtin_nontemporal_load(node + b0);
    float ef0 = __builtin_nontemporal_load(edgef + b0);
    float nd1 = __builtin_nontemporal_load(node + b1);
    float ef1 = __builtin_nontemporal_load(edgef + b1);

    int cnt = min(counts[(size_t)n * cstride], CAP);
    size_t sbase = (size_t)n * CAP;

    float a0[8], a1[8];
#pragma unroll
    for (int i = 0; i < 8; ++i) { a0[i] = 0.f; a1[i] = 0.f; }

    int last = cnt - 1;
    int nch = (cnt + 31) >> 5;        // chunks of 32 entries; avg cnt=32 -> 1
    for (int c = 0; c < nch; ++c) {
        int k0 = sub + c * 32;
        unsigned e0 = __builtin_nontemporal_load(slots + sbase + min(k0,      last));
        unsigned e1 = __builtin_nontemporal_load(slots + sbase + min(k0 + 8,  last));
        unsigned e2 = __builtin_nontemporal_load(slots + sbase + min(k0 + 16, last));
        unsigned e3 = __builtin_nontemporal_load(slots + sbase + min(k0 + 24, last));
        float g0 = (k0      < cnt) ? bfhi2f(e0) : 0.f;
        float g1 = (k0 + 8  < cnt) ? bfhi2f(e1) : 0.f;
        float g2 = (k0 + 16 < cnt) ? bfhi2f(e2) : 0.f;
        float g3 = (k0 + 24 < cnt) ? bfhi2f(e3) : 0.f;
        unsigned m0 = e0 & 0xFFFFu, m1 = e1 & 0xFFFFu;
        unsigned m2 = e2 & 0xFFFFu, m3 = e3 & 0xFFFFu;
        uint4 r00 = P4[(size_t)m0 * 16 + j];
        uint4 r10 = P4[(size_t)m0 * 16 + 8 + j];
        uint4 r01 = P4[(size_t)m1 * 16 + j];
        uint4 r11 = P4[(size_t)m1 * 16 + 8 + j];
        uint4 r02 = P4[(size_t)m2 * 16 + j];
        uint4 r12 = P4[(size_t)m2 * 16 + 8 + j];
        uint4 r03 = P4[(size_t)m3 * 16 + j];
        uint4 r13 = P4[(size_t)m3 * 16 + 8 + j];
        acc8(g0, r00, a0); acc8(g0, r10, a1);
        acc8(g1, r01, a0); acc8(g1, r11, a1);
        acc8(g2, r02, a0); acc8(g2, r12, a1);
        acc8(g3, r03, a0); acc8(g3, r13, a1);
    }

#pragma unroll
    for (int m = 8; m <= 32; m <<= 1) {
#pragma unroll
        for (int i = 0; i < 8; ++i) {
            a0[i] += __shfl_xor(a0[i], m, 64);
            a1[i] += __shfl_xor(a1[i], m, 64);
        }
    }

    if (sub == 0) {
        *(float4*)&xs[wave][0][j * 8]     = make_float4(a0[0], a0[1], a0[2], a0[3]);
        *(float4*)&xs[wave][0][j * 8 + 4] = make_float4(a0[4], a0[5], a0[6], a0[7]);
        *(float4*)&xs[wave][1][j * 8]     = make_float4(a1[0], a1[1], a1[2], a1[3]);
        *(float4*)&xs[wave][1][j * 8 + 4] = make_float4(a1[4], a1[5], a1[6], a1[7]);
    }
    // same-wave LDS dependence: compiler inserts lgkmcnt wait; no barrier.
    float s0 = xs[wave][0][lane];
    float s1 = xs[wave][1][lane];

    float y0 = nd0 + s0 + ef0;
    float y1 = nd1 + s1 + ef1;
    float r0 = (y0 >= 0.f) ? y0 : 0.01f * y0;
    float r1 = (y1 >= 0.f) ? y1 : 0.01f * y1;
    __builtin_nontemporal_store(r0, out + b0);
    __builtin_nontemporal_store(r1, out + b1);
}

// ===========================================================================
// LAST-RESORT FALLBACK (tiny ws): atomic scatter + separate gemm (fp32 exact)
// ===========================================================================
__device__ inline void atomic_add4(float* p, float4 val, float g) {
    atomicAdd(p + 0, val.x * g);
    atomicAdd(p + 1, val.y * g);
    atomicAdd(p + 2, val.z * g);
    atomicAdd(p + 3, val.w * g);
}

__global__ __launch_bounds__(256) void scatter_kernel(
    const float* __restrict__ prev,
    const int2* __restrict__ edges,
    const float* __restrict__ status,
    float* __restrict__ nbr)
{
    int idx = blockIdx.x * 256 + threadIdx.x;
    int e = idx >> 4;
    int q = idx & 15;
    if (e >= E) return;
    int2 uv = edges[e];
    float g = status[e];
    const float4* p0 = (const float4*)prev;
    const float4* p1 = (const float4*)(prev + (size_t)N * D);
    float4 pu0 = p0[(size_t)uv.x * 16 + q];
    float4 pv0 = p0[(size_t)uv.y * 16 + q];
    float4 pu1 = p1[(size_t)uv.x * 16 + q];
    float4 pv1 = p1[(size_t)uv.y * 16 + q];
    float* n0 = nbr;
    float* n1 = nbr + (size_t)N * D;
    int off_v = uv.y * D + q * 4;
    int off_u = uv.x * D + q * 4;
    atomic_add4(n0 + off_v, pu0, g);
    atomic_add4(n0 + off_u, pv0, g);
    atomic_add4(n1 + off_v, pu1, g);
    atomic_add4(n1 + off_u, pv1, g);
}

__global__ __launch_bounds__(256) void gemm_relu_kernel(
    float* __restrict__ out,
    const float* __restrict__ node,
    const float* __restrict__ edgef,
    const float* __restrict__ W)
{
    __shared__ float Wl[D][D + 1];
    __shared__ float xs[4][D];
    int t = threadIdx.x;
    for (int i = t; i < D * D; i += 256) Wl[i >> 6][i & 63] = W[i];
    int wave = t >> 6, lane = t & 63;
    int row = blockIdx.x * 4 + wave;
    size_t base = (size_t)row * D;
    float x = out[base + lane];
    xs[wave][lane] = x;
    __syncthreads();
    float acc = 0.f;
#pragma unroll
    for (int d = 0; d < D; ++d) acc += xs[wave][d] * Wl[lane][d];
    float y = node[base + lane] + acc + edgef[base + lane];
    out[base + lane] = (y >= 0.f) ? y : 0.01f * y;
}

// ===========================================================================
extern "C" void kernel_launch(void* const* d_in, const int* in_sizes, int n_in,
                              void* d_out, int out_size, void* d_ws, size_t ws_size,
                              hipStream_t stream) {
    const float* prev   = (const float*)d_in[0];
    const int*   edges  = (const int*)d_in[1];
    const float* node   = (const float*)d_in[2];
    const float* edgef  = (const float*)d_in[3];
    const float* status = (const float*)d_in[4];
    const float* W      = (const float*)d_in[5];
    float* out = (float*)d_out;

    const int2* edges2 = (const int2*)edges;

    // ws: slots[N*CAP] u32 | counts[N*cstride] i32 | P32[N*64] u32
    size_t slots_bytes  = (size_t)N * CAP * sizeof(unsigned);    // 19.2 MB
    size_t p_bytes      = (size_t)N * 64 * sizeof(unsigned);     // 12.8 MB
    size_t counts_pad   = (size_t)N * CSTRIDE_PAD * sizeof(int); // 3.2 MB
    size_t counts_min   = (size_t)N * sizeof(int);               // 0.2 MB

    int cstride;
    size_t counts_bytes;
    if (ws_size >= slots_bytes + counts_pad + p_bytes) {
        cstride = CSTRIDE_PAD; counts_bytes = counts_pad;
    } else if (ws_size >= slots_bytes + counts_min + p_bytes) {
        cstride = 1; counts_bytes = counts_min;
    } else {
        hipMemsetAsync(out, 0, (size_t)B * N * D * sizeof(float), stream);
        scatter_kernel<<<(E * 16) / 256, 256, 0, stream>>>(prev, edges2, status, out);
        gemm_relu_kernel<<<(B * N) / 4, 256, 0, stream>>>(out, node, edgef, W);
        return;
    }

    unsigned* slots = (unsigned*)d_ws;
    int* counts = (int*)((char*)d_ws + slots_bytes);
    unsigned* P32 = (unsigned*)((char*)d_ws + slots_bytes + counts_bytes);

    hipMemsetAsync(counts, 0, counts_bytes, stream);
    build_pgemm_fused<<<TOTAL_GROUPS * 8, 256, 0, stream>>>(
        edges2, status, counts, slots, prev, W, P32, cstride);
    gather_final<<<N / 4, 256, 0, stream>>>(
        (const uint4*)P32, counts, slots, node, edgef, out, cstride);
}